// Round 1
// baseline (878.934 us; speedup 1.0000x reference)
//
#include <hip/hip_runtime.h>
#include <math.h>

// TopKGating: logits = x @ W^T + b  -> softmax(8) -> top-2 (indices, values)
// x: [131072, 1024] f32, W: [8, 1024] f32, b: [8] f32
// out: [N*2] indices (as float) then [N*2] values, flat concat.
//
// R1: register-prefetch staging (T14 async-stage split). Chunk c+1's global
// loads are issued right after chunk c's LDS tile is published, so HBM
// latency hides under chunk-c compute instead of being exposed between the
// two barriers. Grid is 512 blocks -> only 2 blocks/CU co-resident, so
// within-block overlap is the main latency-hiding lever.

#define NUM_TOKENS 131072
#define DIM        1024
#define NE         8
#define TPB        256   // threads per block == tokens per block
#define DC         64    // d-chunk staged per iteration
#define NCH        (DIM / DC)   // 16 chunks
#define RS4        17    // LDS row stride in float4 (68 floats: 64 + 4 pad,
                         // odd in 16B units -> conflict-free ds_read_b128)

__global__ __launch_bounds__(TPB)
void topk_gating_kernel(const float* __restrict__ x,
                        const float* __restrict__ W,
                        const float* __restrict__ b,
                        float* __restrict__ out)
{
    __shared__ float4 lds4[TPB * RS4];   // 69632 B
    const int t    = threadIdx.x;
    const int tok0 = blockIdx.x * TPB;

    const float4* x4 = (const float4*)x;   // [N, 256]
    const float4* W4 = (const float4*)W;   // [8, 256]

    float acc[NE];
#pragma unroll
    for (int e = 0; e < NE; ++e) acc[e] = 0.f;

    // Per-thread staging coords (fixed across chunks):
    // flat = l*TPB + t ; token row r = flat>>4 ; float4 col c4 = flat&15.
    // 16 consecutive lanes read 256B contiguous -> coalesced.

    // Prologue: prefetch chunk 0 into registers.
    float4 pre[16];
#pragma unroll
    for (int l = 0; l < 16; ++l) {
        int flat = l * TPB + t;
        int r    = flat >> 4;
        int c4   = flat & 15;
        pre[l] = x4[(tok0 + r) * (DIM / 4) + c4];
    }

    for (int c = 0; c < NCH; ++c) {
        __syncthreads();  // previous chunk's readers done before overwrite
        // Publish prefetched chunk c to LDS (compiler inserts the vmcnt wait).
#pragma unroll
        for (int l = 0; l < 16; ++l) {
            int flat = l * TPB + t;
            int r    = flat >> 4;
            int c4   = flat & 15;
            lds4[r * RS4 + c4] = pre[l];
        }
        __syncthreads();  // tile visible to all waves

        // Issue chunk c+1's loads NOW; they stay in flight under the compute
        // below and drain at next iteration's ds_write.
        if (c + 1 < NCH) {
#pragma unroll
            for (int l = 0; l < 16; ++l) {
                int flat = l * TPB + t;
                int r    = flat >> 4;
                int c4   = flat & 15;
                pre[l] = x4[(tok0 + r) * (DIM / 4) + (c + 1) * (DC / 4) + c4];
            }
        }

        // Compute chunk c: own token's row from LDS, W via wave-uniform
        // (scalar-cache) loads.
#pragma unroll 4
        for (int j = 0; j < DC / 4; ++j) {
            float4 xv = lds4[t * RS4 + j];
            int d = c * (DC / 4) + j;  // uniform across the wave
#pragma unroll
            for (int e = 0; e < NE; ++e) {
                float4 w = W4[e * (DIM / 4) + d];
                acc[e] = fmaf(xv.x, w.x, acc[e]);
                acc[e] = fmaf(xv.y, w.y, acc[e]);
                acc[e] = fmaf(xv.z, w.z, acc[e]);
                acc[e] = fmaf(xv.w, w.w, acc[e]);
            }
        }
    }

    // Epilogue: bias, stable top-2 on logits (ties -> lower index first,
    // matches lax.top_k), softmax probs for the two winners.
    float logit[NE];
#pragma unroll
    for (int e = 0; e < NE; ++e) logit[e] = acc[e] + b[e];

    float v1 = -INFINITY, v2 = -INFINITY;
    int   i1 = 0,         i2 = 0;
#pragma unroll
    for (int e = 0; e < NE; ++e) {
        float v = logit[e];
        if (v > v1)      { v2 = v1; i2 = i1; v1 = v; i1 = e; }
        else if (v > v2) { v2 = v;  i2 = e; }
    }

    float sum = 0.f;
#pragma unroll
    for (int e = 0; e < NE; ++e) sum += __expf(logit[e] - v1);
    float inv = 1.0f / sum;
    float p1  = inv;                        // exp(v1 - v1) * inv
    float p2  = __expf(v2 - v1) * inv;

    int n = tok0 + t;
    float2* outi = (float2*)out;                            // indices (as float)
    float2* outv = (float2*)(out + 2 * (size_t)NUM_TOKENS); // values
    outi[n] = make_float2((float)i1, (float)i2);
    outv[n] = make_float2(p1, p2);
}

extern "C" void kernel_launch(void* const* d_in, const int* in_sizes, int n_in,
                              void* d_out, int out_size, void* d_ws, size_t ws_size,
                              hipStream_t stream) {
    const float* x = (const float*)d_in[0];
    const float* W = (const float*)d_in[1];
    const float* b = (const float*)d_in[2];
    float* out = (float*)d_out;

    dim3 grid(NUM_TOKENS / TPB);  // 512 blocks
    dim3 block(TPB);
    topk_gating_kernel<<<grid, block, 0, stream>>>(x, W, b, out);
}